// Round 4
// baseline (1805.132 us; speedup 1.0000x reference)
//
#include <hip/hip_runtime.h>

// M=512, N=2048, B=4, L=20, H density 0.02 (row weight ~41, col weight ~10).
#define MM 512
#define NN 2048
#define BB 4
#define LL 20
#define MAXDEG 128      // per-row cap (~13 sigma)
#define EMAX  24576     // padded edge count; actual E ~20973 (25 sigma margin)
#define NT    1024
#define EPT   24        // EMAX / NT, compile-time edges per thread
#define EPSV  1e-6f
#define PADPK ((unsigned)((MM << 16) | NN))

// ---------------- workspace layout (bytes) ----------------
#define WS_ROW_DEG   0          // int[512]
#define WS_ROW_PAD   2048       // int[512*128]
#define WS_ROW_OFFF  264192     // float[512]
#define WS_ROW_PTR   266240     // int[513]
#define WS_EDGE_PACK 268416     // uint[EMAX]  (row<<16 | col)
#define WS_WDE_G     366720     // float[L*EMAX]
#define WS_MWDE_G    2332800    // float[L*EMAX]
// total ~4.30 MB

// ---- k1: one wave per row, ballot-compact H row into padded list ----
__global__ __launch_bounds__(64)
void build_rows(const float* __restrict__ H, int* __restrict__ row_deg,
                int* __restrict__ row_pad, float* __restrict__ row_offf) {
    int i = blockIdx.x, lane = threadIdx.x;
    const float* hrow = H + (size_t)i * NN;
    int base = 0;
    for (int chunk = 0; chunk < NN / 64; ++chunk) {
        int c = chunk * 64 + lane;
        bool pred = hrow[c] != 0.0f;
        unsigned long long mask = __ballot(pred);
        int before = __popcll(mask & ((1ull << lane) - 1ull));
        if (pred) {
            int idx = base + before;
            if (idx < MAXDEG) row_pad[i * MAXDEG + idx] = c;
        }
        base += __popcll(mask);
    }
    if (lane == 0) {
        row_deg[i] = base < MAXDEG ? base : MAXDEG;
        // off-support entries contribute clip(1.0)=1-eps each to the row product
        row_offf[i] = powf(1.0f - EPSV, (float)(NN - base));
    }
}

// ---- k2: exclusive prefix sum of row degrees (single block) ----
__global__ __launch_bounds__(512)
void scan_rows(const int* __restrict__ row_deg, int* __restrict__ row_ptr) {
    __shared__ int tmp[512];
    int t = threadIdx.x;
    tmp[t] = row_deg[t];
    __syncthreads();
    for (int off = 1; off < 512; off <<= 1) {
        int v = (t >= off) ? tmp[t - off] : 0;
        __syncthreads();
        tmp[t] += v;
        __syncthreads();
    }
    if (t == 0) row_ptr[0] = 0;
    row_ptr[t + 1] = tmp[t];
}

// ---- k3: fill packed CSR edge array ----
__global__ __launch_bounds__(64)
void fill_edges(const int* __restrict__ row_deg, const int* __restrict__ row_pad,
                const int* __restrict__ row_ptr, unsigned* __restrict__ edge_pack) {
    int i = blockIdx.x, lane = threadIdx.x;
    int deg = row_deg[i], base = row_ptr[i];
    for (int k = lane; k < deg; k += 64)
        edge_pack[base + k] = ((unsigned)i << 16) | (unsigned)row_pad[i * MAXDEG + k];
}

// ---- k3b: mark padding slots ----
__global__ __launch_bounds__(256)
void pad_edges(const int* __restrict__ row_ptr, unsigned* __restrict__ edge_pack) {
    int e = blockIdx.x * 256 + threadIdx.x;
    if (e < EMAX && e >= row_ptr[MM]) edge_pack[e] = PADPK;
}

// ---- k4: massively parallel gather of dense weights at support ----
__global__ __launch_bounds__(256)
void gather_weights(const float* __restrict__ w_de, const float* __restrict__ mw_de,
                    const unsigned* __restrict__ edge_pack,
                    float* __restrict__ wde_g, float* __restrict__ mwde_g) {
    int idx = blockIdx.x * 256 + threadIdx.x;   // 0 .. L*EMAX-1
    int l = idx / EMAX, e = idx - l * EMAX;
    unsigned pk = edge_pack[e];
    if (pk != PADPK) {
        size_t src = (size_t)l * MM * NN + (size_t)(pk >> 16) * NN + (pk & 0xffffu);
        wde_g[idx]  = w_de[src];
        mwde_g[idx] = mw_de[src];
    } else {
        wde_g[idx]  = 0.0f;   // padded edges carry zero weight -> messages stay 0
        mwde_g[idx] = 0.0f;
    }
}

// ---- main BP kernel: one block per batch; msgs in registers, d in LDS ----
__global__ __launch_bounds__(NT)
void nbp_main(const int* __restrict__ synd, const int* __restrict__ errs,
              const float* __restrict__ llrs,
              const float* __restrict__ w_llr, const float* __restrict__ mw_llr,
              const float* __restrict__ rhos, const float* __restrict__ resw,
              const int* __restrict__ row_ptr, const float* __restrict__ row_offf,
              const unsigned* __restrict__ edge_pack,
              const float* __restrict__ wde_g, const float* __restrict__ mwde_g,
              float* __restrict__ out) {
    __shared__ float d_s[EMAX];          // 96 KB: tanh factors, strided writes
    __shared__ float colsum_s[NN + 1];   // +1 dummy col for padding
    __shared__ float bel_s[NN + 1];
    __shared__ float llrw_s[NN + 1];
    __shared__ float mllrw_s[NN + 1];
    __shared__ float w1_s[NN];           // 1 - err
    __shared__ float sgn_s[MM + 1];      // (-1)^syndrome, +1 dummy row
    __shared__ float rowprod_s[MM + 1];
    __shared__ int   rowptr_s[MM + 1];
    __shared__ float rowofff_s[MM];
    __shared__ float rho_n[LL];
    __shared__ float red[16];

    const int b = blockIdx.x, tid = threadIdx.x;
    const int lane = tid & 63, wave = tid >> 6;

    // ---- init: invariants into LDS ----
    if (tid == 0) {
        float mx = -1e30f;
        for (int l = 0; l < LL; ++l) mx = fmaxf(mx, rhos[l]);
        float s = 0.0f;
        for (int l = 0; l < LL; ++l) { float e = __expf(rhos[l] - mx); rho_n[l] = e; s += e; }
        for (int l = 0; l < LL; ++l) rho_n[l] /= s;
        colsum_s[NN] = 0.0f; llrw_s[NN] = 0.0f; mllrw_s[NN] = 0.0f;
        sgn_s[MM] = 1.0f; rowprod_s[MM] = 0.0f;
    }
    for (int j = tid; j < NN; j += NT) {
        colsum_s[j] = 0.0f;
        w1_s[j] = 1.0f - (float)errs[b * NN + j];
    }
    for (int i = tid; i < MM; i += NT) {
        sgn_s[i] = 1.0f - 2.0f * (float)synd[b * MM + i];
        rowofff_s[i] = row_offf[i];
    }
    for (int i = tid; i <= MM; i += NT) rowptr_s[i] = row_ptr[i];

    // ---- per-thread edge registers (compile-time EPT=24, fully unrolled) ----
    unsigned idx[EPT];
    float msg[EPT], wde[EPT], mwde[EPT];
    #pragma unroll
    for (int k = 0; k < EPT; ++k) {
        idx[k] = edge_pack[tid + k * NT];
        msg[k] = 0.0f;
        wde[k] = wde_g[tid + k * NT];          // prefetch layer 0
    }
    __syncthreads();

    float loss = 0.0f;

    for (int l = 0; l < LL; ++l) {
        const float rw  = resw[l];

        // ---- A: stage llr weights + colsum scatter + prefetch mwde(l) ----
        {
            const float* wl  = w_llr  + l * NN;
            const float* mwl = mw_llr + l * NN;
            for (int j = tid; j < NN; j += NT) {
                float lj = llrs[j];
                llrw_s[j]  = lj * wl[j];
                mllrw_s[j] = lj * mwl[j];
            }
        }
        #pragma unroll
        for (int k = 0; k < EPT; ++k)
            atomicAdd(&colsum_s[idx[k] & 0xffffu], msg[k] * wde[k]);
        {
            const float* mw = mwde_g + (size_t)l * EMAX;
            #pragma unroll
            for (int k = 0; k < EPT; ++k) mwde[k] = mw[tid + k * NT];
        }
        __syncthreads();

        // ---- B: edge-parallel tanh -> d_s ----
        #pragma unroll
        for (int k = 0; k < EPT; ++k) {
            int j = idx[k] & 0xffffu;
            float en = llrw_s[j] + colsum_s[j] - msg[k];
            float t = __expf(en);                  // tanh(en/2) = 1 - 2/(e^en+1)
            float d = 1.0f - 2.0f / (t + 1.0f);
            if (d == 0.0f) d = 1.0f;               // reference: where(d==0, 1, d)
            d = fminf(fmaxf(d, -1.0f + EPSV), 1.0f - EPSV);
            d_s[tid + k * NT] = d;
        }
        __syncthreads();

        // ---- C: thread-per-row product | belief init; prefetch wde(l+1) ----
        if (tid < MM) {
            int base = rowptr_s[tid];
            int deg  = rowptr_s[tid + 1] - base;
            float p0 = 1.0f, p1 = 1.0f;
            int c = 0;
            for (; c + 1 < deg; c += 2) { p0 *= d_s[base + c]; p1 *= d_s[base + c + 1]; }
            if (c < deg) p0 *= d_s[base + c];
            rowprod_s[tid] = p0 * p1 * rowofff_s[tid];
        } else {
            for (int j = tid - MM; j <= NN; j += NT - MM) bel_s[j] = mllrw_s[j];
        }
        if (l + 1 < LL) {
            const float* w = wde_g + (size_t)(l + 1) * EMAX;
            #pragma unroll
            for (int k = 0; k < EPT; ++k) wde[k] = w[tid + k * NT];
        }
        __syncthreads();

        // ---- D: atanh writeback (registers) + belief scatter ----
        #pragma unroll
        for (int k = 0; k < EPT; ++k) {
            int i = idx[k] >> 16, j = idx[k] & 0xffffu;
            float d = d_s[tid + k * NT];
            float r = rowprod_s[i] / d;
            float v = sgn_s[i] * __logf((1.0f + r) / (1.0f - r)) + rw * msg[k]; // 2*atanh
            msg[k] = v;
            atomicAdd(&bel_s[j], v * mwde[k]);
        }
        __syncthreads();

        // ---- E: column-parallel loss + zero colsum for next layer ----
        const float rho = rho_n[l];
        for (int j = tid; j < NN; j += NT) {
            float bel = bel_s[j];
            float sp = fmaxf(bel, 0.0f) + log1pf(__expf(-fabsf(bel)));  // softplus
            loss += rho * (sp - w1_s[j] * bel);
            colsum_s[j] = 0.0f;
        }
        __syncthreads();
    }

    // ---- block reduction of loss, then one global atomic ----
    #pragma unroll
    for (int off = 32; off > 0; off >>= 1) loss += __shfl_down(loss, off);
    if (lane == 0) red[wave] = loss;
    __syncthreads();
    if (wave == 0) {
        float v = (lane < 16) ? red[lane] : 0.0f;
        #pragma unroll
        for (int off = 8; off > 0; off >>= 1) v += __shfl_down(v, off);
        if (lane == 0) atomicAdd(out, v * 0.25f);
    }
}

extern "C" void kernel_launch(void* const* d_in, const int* in_sizes, int n_in,
                              void* d_out, int out_size, void* d_ws, size_t ws_size,
                              hipStream_t stream) {
    const int*   synd  = (const int*)  d_in[0];
    const int*   errs  = (const int*)  d_in[1];
    const float* H     = (const float*)d_in[2];
    const float* llrs  = (const float*)d_in[3];
    const float* w_de  = (const float*)d_in[4];
    const float* w_llr = (const float*)d_in[5];
    const float* mw_de = (const float*)d_in[6];
    const float* mw_llr= (const float*)d_in[7];
    const float* rhos  = (const float*)d_in[8];
    const float* resw  = (const float*)d_in[9];

    char* ws = (char*)d_ws;
    int*      row_deg   = (int*)     (ws + WS_ROW_DEG);
    int*      row_pad   = (int*)     (ws + WS_ROW_PAD);
    float*    row_offf  = (float*)   (ws + WS_ROW_OFFF);
    int*      row_ptr   = (int*)     (ws + WS_ROW_PTR);
    unsigned* edge_pack = (unsigned*)(ws + WS_EDGE_PACK);
    float*    wde_g     = (float*)   (ws + WS_WDE_G);
    float*    mwde_g    = (float*)   (ws + WS_MWDE_G);
    float*    out       = (float*)d_out;

    hipMemsetAsync(d_out, 0, sizeof(float), stream);

    build_rows<<<MM, 64, 0, stream>>>(H, row_deg, row_pad, row_offf);
    scan_rows<<<1, 512, 0, stream>>>(row_deg, row_ptr);
    fill_edges<<<MM, 64, 0, stream>>>(row_deg, row_pad, row_ptr, edge_pack);
    pad_edges<<<EMAX / 256, 256, 0, stream>>>(row_ptr, edge_pack);
    gather_weights<<<(LL * EMAX) / 256, 256, 0, stream>>>(w_de, mw_de, edge_pack,
                                                          wde_g, mwde_g);
    nbp_main<<<BB, NT, 0, stream>>>(synd, errs, llrs, w_llr, mw_llr, rhos, resw,
                                    row_ptr, row_offf, edge_pack, wde_g, mwde_g, out);
}

// Round 6
// 691.536 us; speedup vs baseline: 2.6103x; 2.6103x over previous
//
#include <hip/hip_runtime.h>

// M=512, N=2048, B=4, L=20, H density 0.02 (row weight ~41, col weight ~10).
#define MM 512
#define NN 2048
#define BB 4
#define LL 20
#define MAXDEG 128      // per-row cap (~13 sigma)
#define EMAX  24576     // padded edge count; actual E ~20973
#define NT    1024
#define EPT   24        // contiguous CSC slots per thread
#define EPSV  1e-6f
#define PADPK ((unsigned)((MM << 16) | NN))

// ---------------- workspace layout (bytes) ----------------
#define WS_ROW_DEG   0          // int[512]
#define WS_ROW_PAD   2048       // int[512*128]
#define WS_ROW_OFFF  264192     // float[512]
#define WS_ROW_PTR   266240     // int[513]
#define WS_COL_CNT   268416     // int[2048]
#define WS_COL_PTR   276608     // int[2049]
#define WS_EDGE_CSR  284928     // uint[EMAX]
#define WS_EDGE_CSC  383232     // uint[EMAX]
#define WS_PERM      481536     // ushort[EMAX]  (CSC slot -> CSR slot)
#define WS_WDE_G     530688     // float[L*EMAX] (CSC order)
#define WS_MWDE_G    2496768    // float[L*EMAX] (CSC order)
// total ~4.46 MB

// ---- k1: one wave per row, ballot-compact H row into padded list ----
__global__ __launch_bounds__(64)
void build_rows(const float* __restrict__ H, int* __restrict__ row_deg,
                int* __restrict__ row_pad, float* __restrict__ row_offf) {
    int i = blockIdx.x, lane = threadIdx.x;
    const float* hrow = H + (size_t)i * NN;
    int base = 0;
    for (int chunk = 0; chunk < NN / 64; ++chunk) {
        int c = chunk * 64 + lane;
        bool pred = hrow[c] != 0.0f;
        unsigned long long mask = __ballot(pred);
        int before = __popcll(mask & ((1ull << lane) - 1ull));
        if (pred) {
            int idx = base + before;
            if (idx < MAXDEG) row_pad[i * MAXDEG + idx] = c;
        }
        base += __popcll(mask);
    }
    if (lane == 0) {
        row_deg[i] = base < MAXDEG ? base : MAXDEG;
        // off-support entries contribute clip(1.0)=1-eps each to the row product
        row_offf[i] = powf(1.0f - EPSV, (float)(NN - base));
    }
}

// ---- k2: exclusive prefix sum of row degrees (single block) ----
__global__ __launch_bounds__(512)
void scan_rows(const int* __restrict__ row_deg, int* __restrict__ row_ptr) {
    __shared__ int tmp[512];
    int t = threadIdx.x;
    tmp[t] = row_deg[t];
    __syncthreads();
    for (int off = 1; off < 512; off <<= 1) {
        int v = (t >= off) ? tmp[t - off] : 0;
        __syncthreads();
        tmp[t] += v;
        __syncthreads();
    }
    if (t == 0) row_ptr[0] = 0;
    row_ptr[t + 1] = tmp[t];
}

// ---- k3: fill CSR edge list + count columns (col_cnt pre-zeroed) ----
__global__ __launch_bounds__(64)
void fill_csr(const int* __restrict__ row_deg, const int* __restrict__ row_pad,
              const int* __restrict__ row_ptr, unsigned* __restrict__ edge_csr,
              int* __restrict__ col_cnt) {
    int i = blockIdx.x, lane = threadIdx.x;
    int deg = row_deg[i], base = row_ptr[i];
    for (int k = lane; k < deg; k += 64) {
        int j = row_pad[i * MAXDEG + k];
        edge_csr[base + k] = ((unsigned)i << 16) | (unsigned)j;
        atomicAdd(&col_cnt[j], 1);
    }
}

// ---- k4: exclusive prefix sum of col counts; zero col_cnt for reuse ----
__global__ __launch_bounds__(1024)
void scan_cols(int* __restrict__ col_cnt, int* __restrict__ col_ptr,
               const int* __restrict__ row_ptr) {
    __shared__ int tmp[1024];
    int t = threadIdx.x;
    int a = col_cnt[2 * t], bcnt = col_cnt[2 * t + 1];
    tmp[t] = a + bcnt;
    __syncthreads();
    for (int off = 1; off < 1024; off <<= 1) {
        int v = (t >= off) ? tmp[t - off] : 0;
        __syncthreads();
        tmp[t] += v;
        __syncthreads();
    }
    int excl = tmp[t] - (a + bcnt);
    col_ptr[2 * t]     = excl;
    col_ptr[2 * t + 1] = excl + a;
    col_cnt[2 * t] = 0; col_cnt[2 * t + 1] = 0;
    if (t == 0) col_ptr[NN] = row_ptr[MM];
}

// ---- k5: build CSC edge list + CSC->CSR permutation; pads at tail ----
__global__ __launch_bounds__(256)
void build_csc(const unsigned* __restrict__ edge_csr, const int* __restrict__ row_ptr,
               const int* __restrict__ col_ptr, int* __restrict__ col_cnt,
               unsigned* __restrict__ edge_csc, unsigned short* __restrict__ perm) {
    int e = blockIdx.x * 256 + threadIdx.x;
    if (e >= EMAX) return;
    int E = row_ptr[MM];
    if (e < E) {
        unsigned pk = edge_csr[e];
        int j = pk & 0xffffu;
        int pos = col_ptr[j] + atomicAdd(&col_cnt[j], 1);
        edge_csc[pos] = pk;
        perm[pos] = (unsigned short)e;
    } else {
        edge_csc[e] = PADPK;
        perm[e] = (unsigned short)e;
    }
}

// ---- k6: massively parallel gather of dense weights (CSC order) ----
__global__ __launch_bounds__(256)
void gather_weights(const float* __restrict__ w_de, const float* __restrict__ mw_de,
                    const unsigned* __restrict__ edge_csc,
                    float* __restrict__ wde_g, float* __restrict__ mwde_g) {
    int idx = blockIdx.x * 256 + threadIdx.x;   // 0 .. L*EMAX-1
    int l = idx / EMAX, e = idx - l * EMAX;
    unsigned pk = edge_csc[e];
    if (pk != PADPK) {
        size_t src = (size_t)l * MM * NN + (size_t)(pk >> 16) * NN + (pk & 0xffffu);
        wde_g[idx]  = w_de[src];
        mwde_g[idx] = mw_de[src];
    } else {
        wde_g[idx]  = 0.0f;   // padded edges carry zero weight -> messages stay 0
        mwde_g[idx] = 0.0f;
    }
}

// ---- main BP kernel: one block per batch; contiguous CSC edge ownership ----
__global__ __launch_bounds__(NT, 4)   // 4 waves/EU -> 128 VGPR cap, no spills
void nbp_main(const int* __restrict__ synd, const int* __restrict__ errs,
              const float* __restrict__ llrs,
              const float* __restrict__ w_llr, const float* __restrict__ mw_llr,
              const float* __restrict__ rhos, const float* __restrict__ resw,
              const int* __restrict__ row_ptr, const float* __restrict__ row_offf,
              const unsigned* __restrict__ edge_csc,
              const unsigned short* __restrict__ perm_g,
              const float* __restrict__ wde_g, const float* __restrict__ mwde_g,
              float* __restrict__ out) {
    __shared__ float d_s[EMAX];              // 96 KB, CSR-indexed tanh factors
    __shared__ unsigned short perm_s[EMAX];  // 48 KB, CSC slot -> CSR slot
    __shared__ float cb_s[NN + 1];           // colsum, reused as beliefs
    __shared__ float rowprod_s[MM + 1];      // sgn * offf * prod(d) per row
    __shared__ float rho_n[LL];
    __shared__ float red[16];

    const int b = blockIdx.x, tid = threadIdx.x;
    const int lane = tid & 63, wave = tid >> 6;
    const int base = tid * EPT;
    const int* synd_b = synd + b * MM;
    const int* err_b  = errs + b * NN;

    // stage perm into LDS (coalesced u32 pairs)
    {
        const unsigned* pg = (const unsigned*)perm_g;
        unsigned* ps = (unsigned*)perm_s;
        for (int k = tid; k < EMAX / 2; k += NT) ps[k] = pg[k];
    }
    if (tid == 0) {
        float mx = -1e30f;
        for (int l = 0; l < LL; ++l) mx = fmaxf(mx, rhos[l]);
        float s = 0.0f;
        for (int l = 0; l < LL; ++l) { float e = __expf(rhos[l] - mx); rho_n[l] = e; s += e; }
        for (int l = 0; l < LL; ++l) rho_n[l] /= s;
        cb_s[NN] = 0.0f;         // dummy column for pad edges
        rowprod_s[MM] = 0.0f;    // dummy row for pad edges
    }
    // A1(layer 0): colsum init = llrs * w_llr
    for (int j = tid; j < NN; j += NT) cb_s[j] = llrs[j] * w_llr[j];

    // persistent per-thread state: packed (row,col) + message, 48 VGPRs
    unsigned idx[EPT];
    float msg[EPT];
    {
        const uint4* ep = (const uint4*)(edge_csc + base);
        #pragma unroll
        for (int k = 0; k < EPT / 4; ++k) {
            uint4 u = ep[k];
            idx[4*k] = u.x; idx[4*k+1] = u.y; idx[4*k+2] = u.z; idx[4*k+3] = u.w;
        }
        #pragma unroll
        for (int k = 0; k < EPT; ++k) msg[k] = 0.0f;
    }
    __syncthreads();

    float loss = 0.0f;

    for (int l = 0; l < LL; ++l) {
        const float rw  = resw[l];
        const float rho = rho_n[l];

        // ---- A2: colsum scatter, run-compressed (~3 atomics/thread) ----
        {
            const float4* wp = (const float4*)(wde_g + (size_t)l * EMAX + base);
            float wv[EPT];
            #pragma unroll
            for (int k = 0; k < EPT / 4; ++k) {
                float4 f = wp[k];
                wv[4*k] = f.x; wv[4*k+1] = f.y; wv[4*k+2] = f.z; wv[4*k+3] = f.w;
            }
            float acc = msg[0] * wv[0];
            int pj = idx[0] & 0xffffu;
            #pragma unroll
            for (int k = 1; k < EPT; ++k) {
                int j = idx[k] & 0xffffu;
                if (j != pj) { atomicAdd(&cb_s[pj], acc); acc = 0.0f; pj = j; }
                acc += msg[k] * wv[k];
            }
            atomicAdd(&cb_s[pj], acc);
        }
        __syncthreads();

        // ---- B: per-edge tanh, scatter d to CSR position via perm ----
        {
            int pj = idx[0] & 0xffffu;
            float cs = cb_s[pj];
            #pragma unroll
            for (int k = 0; k < EPT; ++k) {
                int j = idx[k] & 0xffffu;
                if (j != pj) { cs = cb_s[j]; pj = j; }
                float en = cs - msg[k];
                float t = __expf(en);                             // e^en
                float d = 1.0f - 2.0f * __builtin_amdgcn_rcpf(t + 1.0f);
                if (d == 0.0f) d = 1.0f;                          // ref: where(d==0,1,d)
                d = fminf(fmaxf(d, -1.0f + EPSV), 1.0f - EPSV);
                d_s[perm_s[base + k]] = d;
            }
        }
        __syncthreads();

        // ---- C: thread-per-row product (tid<512) | belief init (tid>=512) ----
        if (tid < MM) {
            int rb = row_ptr[tid];
            int deg = row_ptr[tid + 1] - rb;
            float p0 = 1.0f, p1 = 1.0f, p2 = 1.0f, p3 = 1.0f;
            int c = 0;
            for (; c + 3 < deg; c += 4) {
                p0 *= d_s[rb + c];     p1 *= d_s[rb + c + 1];
                p2 *= d_s[rb + c + 2]; p3 *= d_s[rb + c + 3];
            }
            for (; c < deg; ++c) p0 *= d_s[rb + c];
            float sg = 1.0f - 2.0f * (float)synd_b[tid];
            rowprod_s[tid] = p0 * p1 * p2 * p3 * row_offf[tid] * sg;  // sgn folded in
        } else {
            int t2 = tid - MM;                       // 0..511, coalesced cols
            const float* mwl = mw_llr + l * NN;
            #pragma unroll
            for (int q = 0; q < 4; ++q) {
                int j = t2 + q * MM;
                cb_s[j] = llrs[j] * mwl[j];          // colsum is dead; reuse as bel
            }
        }
        __syncthreads();

        // ---- D: atanh + msg writeback + belief scatter (run-compressed) ----
        {
            const float4* mp = (const float4*)(mwde_g + (size_t)l * EMAX + base);
            float mv[EPT];
            #pragma unroll
            for (int k = 0; k < EPT / 4; ++k) {
                float4 f = mp[k];
                mv[4*k] = f.x; mv[4*k+1] = f.y; mv[4*k+2] = f.z; mv[4*k+3] = f.w;
            }
            float acc = 0.0f;
            int pj = idx[0] & 0xffffu;
            #pragma unroll
            for (int k = 0; k < EPT; ++k) {
                int i = idx[k] >> 16;
                int j = idx[k] & 0xffffu;
                float d = d_s[perm_s[base + k]];
                float r = rowprod_s[i] * __builtin_amdgcn_rcpf(d);
                // sgn*2*atanh(x) = 2*atanh(sgn*x) (odd fn; sgn folded into rowprod)
                float v = __logf(1.0f + r) - __logf(1.0f - r) + rw * msg[k];
                msg[k] = v;
                if (j != pj) { atomicAdd(&cb_s[pj], acc); acc = 0.0f; pj = j; }
                acc += v * mv[k];
            }
            atomicAdd(&cb_s[pj], acc);
        }
        __syncthreads();

        // ---- E + A1(l+1): loss from beliefs, then re-init colsum in place ----
        {
            const float* wl_next = w_llr + (l + 1 < LL ? (l + 1) * NN : 0);
            for (int j = tid; j < NN; j += NT) {
                float bel = cb_s[j];
                float sp = fmaxf(bel, 0.0f) + log1pf(__expf(-fabsf(bel)));  // softplus
                loss += rho * (sp - (1.0f - (float)err_b[j]) * bel);
                cb_s[j] = llrs[j] * wl_next[j];
            }
        }
        __syncthreads();
    }

    // ---- block reduction of loss, then one global atomic ----
    #pragma unroll
    for (int off = 32; off > 0; off >>= 1) loss += __shfl_down(loss, off);
    if (lane == 0) red[wave] = loss;
    __syncthreads();
    if (wave == 0) {
        float v = (lane < 16) ? red[lane] : 0.0f;
        #pragma unroll
        for (int off = 8; off > 0; off >>= 1) v += __shfl_down(v, off);
        if (lane == 0) atomicAdd(out, v * 0.25f);
    }
}

extern "C" void kernel_launch(void* const* d_in, const int* in_sizes, int n_in,
                              void* d_out, int out_size, void* d_ws, size_t ws_size,
                              hipStream_t stream) {
    const int*   synd  = (const int*)  d_in[0];
    const int*   errs  = (const int*)  d_in[1];
    const float* H     = (const float*)d_in[2];
    const float* llrs  = (const float*)d_in[3];
    const float* w_de  = (const float*)d_in[4];
    const float* w_llr = (const float*)d_in[5];
    const float* mw_de = (const float*)d_in[6];
    const float* mw_llr= (const float*)d_in[7];
    const float* rhos  = (const float*)d_in[8];
    const float* resw  = (const float*)d_in[9];

    char* ws = (char*)d_ws;
    int*            row_deg  = (int*)           (ws + WS_ROW_DEG);
    int*            row_pad  = (int*)           (ws + WS_ROW_PAD);
    float*          row_offf = (float*)         (ws + WS_ROW_OFFF);
    int*            row_ptr  = (int*)           (ws + WS_ROW_PTR);
    int*            col_cnt  = (int*)           (ws + WS_COL_CNT);
    int*            col_ptr  = (int*)           (ws + WS_COL_PTR);
    unsigned*       edge_csr = (unsigned*)      (ws + WS_EDGE_CSR);
    unsigned*       edge_csc = (unsigned*)      (ws + WS_EDGE_CSC);
    unsigned short* perm     = (unsigned short*)(ws + WS_PERM);
    float*          wde_g    = (float*)         (ws + WS_WDE_G);
    float*          mwde_g   = (float*)         (ws + WS_MWDE_G);
    float*          out      = (float*)d_out;

    hipMemsetAsync(col_cnt, 0, NN * sizeof(int), stream);
    hipMemsetAsync(d_out, 0, sizeof(float), stream);

    build_rows<<<MM, 64, 0, stream>>>(H, row_deg, row_pad, row_offf);
    scan_rows<<<1, 512, 0, stream>>>(row_deg, row_ptr);
    fill_csr<<<MM, 64, 0, stream>>>(row_deg, row_pad, row_ptr, edge_csr, col_cnt);
    scan_cols<<<1, 1024, 0, stream>>>(col_cnt, col_ptr, row_ptr);
    build_csc<<<EMAX / 256, 256, 0, stream>>>(edge_csr, row_ptr, col_ptr, col_cnt,
                                              edge_csc, perm);
    gather_weights<<<(LL * EMAX) / 256, 256, 0, stream>>>(w_de, mw_de, edge_csc,
                                                          wde_g, mwde_g);
    nbp_main<<<BB, NT, 0, stream>>>(synd, errs, llrs, w_llr, mw_llr, rhos, resw,
                                    row_ptr, row_offf, edge_csc, perm,
                                    wde_g, mwde_g, out);
}

// Round 7
// 484.187 us; speedup vs baseline: 3.7282x; 1.4282x over previous
//
#include <hip/hip_runtime.h>

// M=512, N=2048, B=4, L=20, H density 0.02 (row weight ~41, col weight ~10).
#define MM 512
#define NN 2048
#define BB 4
#define LL 20
#define MAXDEG 128      // per-row cap (~13 sigma)
#define EMAX  24576     // padded edge cap; actual E ~20973
#define NT    1024
#define RR    8         // blocks per batch (row-partitioned)
#define ROWSB 64        // MM / RR rows per block
#define EPTB  4         // edge slots per thread (4*1024=4096 >= ~2620+29sigma)
#define COLSB 256       // NN / RR loss columns per block
#define EPSV  1e-6f

// ---------------- workspace layout (bytes) ----------------
#define WS_ROW_DEG   0          // int[512]
#define WS_ROW_PAD   2048       // int[512*128]
#define WS_ROW_OFFF  264192     // float[512]
#define WS_ROW_PTR   266240     // int[513]
#define WS_EDGE_CSR  268416     // uint[EMAX]  (row<<16 | col), CSR order
#define WS_WDE_G     366720     // float[L*EMAX] (CSR order)
#define WS_MWDE_G    2332800    // float[L*EMAX]
#define WS_COLPART   4298880    // float[B*RR*NN] colsum partials
#define WS_BELPART   4561024    // float[B*RR*NN] belief partials
#define WS_BAR       4823168    // int[B*64] barrier counters (memset 0 each launch)
// total ~4.83 MB

// ---- k1: one wave per row, ballot-compact H row into padded list ----
__global__ __launch_bounds__(64)
void build_rows(const float* __restrict__ H, int* __restrict__ row_deg,
                int* __restrict__ row_pad, float* __restrict__ row_offf) {
    int i = blockIdx.x, lane = threadIdx.x;
    const float* hrow = H + (size_t)i * NN;
    int base = 0;
    for (int chunk = 0; chunk < NN / 64; ++chunk) {
        int c = chunk * 64 + lane;
        bool pred = hrow[c] != 0.0f;
        unsigned long long mask = __ballot(pred);
        int before = __popcll(mask & ((1ull << lane) - 1ull));
        if (pred) {
            int idx = base + before;
            if (idx < MAXDEG) row_pad[i * MAXDEG + idx] = c;
        }
        base += __popcll(mask);
    }
    if (lane == 0) {
        row_deg[i] = base < MAXDEG ? base : MAXDEG;
        // off-support entries contribute clip(1.0)=1-eps each to the row product
        row_offf[i] = powf(1.0f - EPSV, (float)(NN - base));
    }
}

// ---- k2: exclusive prefix sum of row degrees (single block) ----
__global__ __launch_bounds__(512)
void scan_rows(const int* __restrict__ row_deg, int* __restrict__ row_ptr) {
    __shared__ int tmp[512];
    int t = threadIdx.x;
    tmp[t] = row_deg[t];
    __syncthreads();
    for (int off = 1; off < 512; off <<= 1) {
        int v = (t >= off) ? tmp[t - off] : 0;
        __syncthreads();
        tmp[t] += v;
        __syncthreads();
    }
    if (t == 0) row_ptr[0] = 0;
    row_ptr[t + 1] = tmp[t];
}

// ---- k3: fill CSR edge list ----
__global__ __launch_bounds__(64)
void fill_csr(const int* __restrict__ row_deg, const int* __restrict__ row_pad,
              const int* __restrict__ row_ptr, unsigned* __restrict__ edge_csr) {
    int i = blockIdx.x, lane = threadIdx.x;
    int deg = row_deg[i], base = row_ptr[i];
    for (int k = lane; k < deg; k += 64)
        edge_csr[base + k] = ((unsigned)i << 16) | (unsigned)row_pad[i * MAXDEG + k];
}

// ---- k4: massively parallel gather of dense weights (CSR order) ----
__global__ __launch_bounds__(256)
void gather_weights(const float* __restrict__ w_de, const float* __restrict__ mw_de,
                    const unsigned* __restrict__ edge_csr, const int* __restrict__ row_ptr,
                    float* __restrict__ wde_g, float* __restrict__ mwde_g) {
    int idx = blockIdx.x * 256 + threadIdx.x;   // 0 .. L*EMAX-1
    int l = idx / EMAX, e = idx - l * EMAX;
    if (e < row_ptr[MM]) {
        unsigned pk = edge_csr[e];
        size_t src = (size_t)l * MM * NN + (size_t)(pk >> 16) * NN + (pk & 0xffffu);
        wde_g[idx]  = w_de[src];
        mwde_g[idx] = mw_de[src];
    } else {
        wde_g[idx]  = 0.0f;   // tail slots: defined zeros (never used, never NaN)
        mwde_g[idx] = 0.0f;
    }
}

// ---- device-scope barrier across the RR blocks of one batch ----
// Fresh counter per instance (no ABA). tid0: release fence -> add -> spin -> acquire.
__device__ __forceinline__ void grid_barrier(int* ctr) {
    __syncthreads();
    if (threadIdx.x == 0) {
        __threadfence();   // push this block's stores to device-visible point
        __hip_atomic_fetch_add(ctr, 1, __ATOMIC_RELAXED, __HIP_MEMORY_SCOPE_AGENT);
        while (__hip_atomic_load(ctr, __ATOMIC_RELAXED, __HIP_MEMORY_SCOPE_AGENT) < RR)
            __builtin_amdgcn_s_sleep(1);
        __threadfence();   // invalidate stale L1/L2 before reading peers' data
    }
    __syncthreads();
}

// ---- main BP kernel: 32 blocks = 4 batches x 8 row-partitions ----
__global__ __launch_bounds__(NT, 4)
void nbp_main(const int* __restrict__ synd, const int* __restrict__ errs,
              const float* __restrict__ llrs,
              const float* __restrict__ w_llr, const float* __restrict__ mw_llr,
              const float* __restrict__ rhos, const float* __restrict__ resw,
              const int* __restrict__ row_ptr, const float* __restrict__ row_offf,
              const unsigned* __restrict__ edge_csr,
              const float* __restrict__ wde_g, const float* __restrict__ mwde_g,
              float* __restrict__ colpart, float* __restrict__ belpart,
              int* __restrict__ bar, float* __restrict__ out) {
    __shared__ float d_sb[EPTB * NT];     // 16 KB, block-local CSR d, stride-1
    __shared__ float colsum_s[NN];        // 8 KB
    __shared__ float bel_s[NN];           // 8 KB (edge contributions only)
    __shared__ float llrs_s[NN];          // 8 KB
    __shared__ float rowprod_s[ROWSB];
    __shared__ float rp_coef[ROWSB];      // row_offf * (-1)^syndrome
    __shared__ int   rowptr_s[ROWSB + 1];
    __shared__ float rho_n[LL];
    __shared__ float red[16];

    const int blk = blockIdx.x;
    const int b = blk & 3, r = blk >> 2;  // same-batch blocks 4 apart -> 2 XCDs/batch
    const int i0 = r * ROWSB;
    const int tid = threadIdx.x;
    const int lane = tid & 63, wave = tid >> 6;

    float* colpart_b = colpart + (size_t)b * RR * NN;
    float* belpart_b = belpart + (size_t)b * RR * NN;
    int*   bar_b     = bar + b * 64;
    int    bi = 0;

    // ---- prologue ----
    if (tid == 0) {
        float mx = -1e30f;
        for (int l = 0; l < LL; ++l) mx = fmaxf(mx, rhos[l]);
        float s = 0.0f;
        for (int l = 0; l < LL; ++l) { float e = __expf(rhos[l] - mx); rho_n[l] = e; s += e; }
        for (int l = 0; l < LL; ++l) rho_n[l] /= s;
    }
    if (tid < ROWSB) {
        int i = i0 + tid;
        rowptr_s[tid] = row_ptr[i];
        rp_coef[tid] = row_offf[i] * (1.0f - 2.0f * (float)synd[b * MM + i]);
    }
    if (tid == ROWSB) rowptr_s[ROWSB] = row_ptr[i0 + ROWSB];
    for (int j = tid; j < NN; j += NT) llrs_s[j] = llrs[j];
    __syncthreads();

    const int e_lo = rowptr_s[0], e_hi = rowptr_s[ROWSB];
    const int ebase = e_lo + tid;

    // per-thread edge state: packed (local_row<<16 | col), message, weights
    unsigned idx[EPTB];
    float msg[EPTB], wv[EPTB], mv[EPTB], wvn[EPTB], d_r[EPTB];
    #pragma unroll
    for (int k = 0; k < EPTB; ++k) {
        int e = ebase + k * NT;
        int eld = e < e_hi ? e : e_lo;
        idx[k] = edge_csr[eld] - ((unsigned)i0 << 16);
        msg[k] = 0.0f;
        wv[k] = 0.0f; wvn[k] = 0.0f;
    }

    float loss = 0.0f;

    for (int l = 0; l < LL; ++l) {
        const float rw = resw[l];

        // ---- A: total colsum into colsum_s ----
        if (l == 0) {
            // msgs are all zero -> edge term vanishes; no exchange needed
            const float* wl = w_llr;   // layer 0
            for (int j = tid; j < NN; j += NT) colsum_s[j] = llrs_s[j] * wl[j];
            __syncthreads();
        } else {
            // colsum_s was zeroed in phase C of the previous layer
            #pragma unroll
            for (int k = 0; k < EPTB; ++k) {
                if (ebase + k * NT < e_hi)
                    atomicAdd(&colsum_s[idx[k] & 0xffffu], msg[k] * wv[k]);
            }
            __syncthreads();
            for (int j = tid; j < NN; j += NT) colpart_b[r * NN + j] = colsum_s[j];
            grid_barrier(&bar_b[bi]); ++bi;
            const float* wl = w_llr + l * NN;
            for (int j = tid; j < NN; j += NT) {
                float s = llrs_s[j] * wl[j];
                const float* cp = colpart_b + j;
                #pragma unroll
                for (int r2 = 0; r2 < RR; ++r2) s += cp[r2 * NN];
                colsum_s[j] = s;
            }
            __syncthreads();
        }

        // ---- B: per-edge tanh -> d (registers + stride-1 LDS) ----
        {   // prefetch mwde(l), used in D
            const float* mwl = mwde_g + (size_t)l * EMAX;
            #pragma unroll
            for (int k = 0; k < EPTB; ++k) {
                int e = ebase + k * NT;
                mv[k] = mwl[e < EMAX ? e : EMAX - 1];
            }
        }
        #pragma unroll
        for (int k = 0; k < EPTB; ++k) {
            int j = idx[k] & 0xffffu;
            float en = colsum_s[j] - msg[k];
            float t = __expf(en);                             // tanh(en/2)=1-2/(e^en+1)
            float d = 1.0f - 2.0f * __builtin_amdgcn_rcpf(t + 1.0f);
            if (d == 0.0f) d = 1.0f;                          // ref: where(d==0,1,d)
            d = fminf(fmaxf(d, -1.0f + EPSV), 1.0f - EPSV);
            d_r[k] = d;
            if (ebase + k * NT < e_hi) d_sb[tid + k * NT] = d;
        }
        __syncthreads();

        // ---- C: local row products | zero bel_s + colsum_s for next uses ----
        if (tid < ROWSB) {
            int s = rowptr_s[tid] - e_lo;
            int deg = rowptr_s[tid + 1] - rowptr_s[tid];
            float p0 = 1.0f, p1 = 1.0f, p2 = 1.0f, p3 = 1.0f;
            int c = 0;
            for (; c + 3 < deg; c += 4) {
                p0 *= d_sb[s + c];     p1 *= d_sb[s + c + 1];
                p2 *= d_sb[s + c + 2]; p3 *= d_sb[s + c + 3];
            }
            for (; c < deg; ++c) p0 *= d_sb[s + c];
            rowprod_s[tid] = p0 * p1 * p2 * p3 * rp_coef[tid];   // sign folded in
        } else {
            for (int j = tid - ROWSB; j < NN; j += NT - ROWSB) {
                bel_s[j] = 0.0f;
                colsum_s[j] = 0.0f;
            }
        }
        __syncthreads();

        // ---- D: atanh + msg update + local belief scatter ----
        if (l + 1 < LL) {   // prefetch wde(l+1), used in next A
            const float* wl = wde_g + (size_t)(l + 1) * EMAX;
            #pragma unroll
            for (int k = 0; k < EPTB; ++k) {
                int e = ebase + k * NT;
                wvn[k] = wl[e < EMAX ? e : EMAX - 1];
            }
        }
        #pragma unroll
        for (int k = 0; k < EPTB; ++k) {
            int il = idx[k] >> 16;
            int j  = idx[k] & 0xffffu;
            float rq = rowprod_s[il] * __builtin_amdgcn_rcpf(d_r[k]);
            // sgn*2*atanh(x) = 2*atanh(sgn*x); sgn folded into rp_coef
            float v = __logf(1.0f + rq) - __logf(1.0f - rq) + rw * msg[k];
            msg[k] = v;
            if (ebase + k * NT < e_hi) atomicAdd(&bel_s[j], v * mv[k]);
        }
        __syncthreads();
        for (int j = tid; j < NN; j += NT) belpart_b[r * NN + j] = bel_s[j];
        grid_barrier(&bar_b[bi]); ++bi;

        // ---- E: loss on this block's column slice ----
        if (tid < COLSB) {
            int j = r * COLSB + tid;
            float bel = llrs_s[j] * mw_llr[l * NN + j];
            const float* bp = belpart_b + j;
            #pragma unroll
            for (int r2 = 0; r2 < RR; ++r2) bel += bp[r2 * NN];
            float sp = fmaxf(bel, 0.0f) + log1pf(__expf(-fabsf(bel)));  // softplus
            loss += rho_n[l] * (sp - (1.0f - (float)errs[b * NN + j]) * bel);
        }
        #pragma unroll
        for (int k = 0; k < EPTB; ++k) wv[k] = wvn[k];
        // no barrier: next A's atomics hit colsum_s (zeroed in C); E reads belpart,
        // which no block overwrites until after the next grid barrier.
    }

    // ---- block reduction of loss, then one global atomic ----
    #pragma unroll
    for (int off = 32; off > 0; off >>= 1) loss += __shfl_down(loss, off);
    if (lane == 0) red[wave] = loss;
    __syncthreads();
    if (wave == 0) {
        float v = (lane < 16) ? red[lane] : 0.0f;
        #pragma unroll
        for (int off = 8; off > 0; off >>= 1) v += __shfl_down(v, off);
        if (lane == 0) atomicAdd(out, v * 0.25f);
    }
}

extern "C" void kernel_launch(void* const* d_in, const int* in_sizes, int n_in,
                              void* d_out, int out_size, void* d_ws, size_t ws_size,
                              hipStream_t stream) {
    const int*   synd  = (const int*)  d_in[0];
    const int*   errs  = (const int*)  d_in[1];
    const float* H     = (const float*)d_in[2];
    const float* llrs  = (const float*)d_in[3];
    const float* w_de  = (const float*)d_in[4];
    const float* w_llr = (const float*)d_in[5];
    const float* mw_de = (const float*)d_in[6];
    const float* mw_llr= (const float*)d_in[7];
    const float* rhos  = (const float*)d_in[8];
    const float* resw  = (const float*)d_in[9];

    char* ws = (char*)d_ws;
    int*      row_deg  = (int*)     (ws + WS_ROW_DEG);
    int*      row_pad  = (int*)     (ws + WS_ROW_PAD);
    float*    row_offf = (float*)   (ws + WS_ROW_OFFF);
    int*      row_ptr  = (int*)     (ws + WS_ROW_PTR);
    unsigned* edge_csr = (unsigned*)(ws + WS_EDGE_CSR);
    float*    wde_g    = (float*)   (ws + WS_WDE_G);
    float*    mwde_g   = (float*)   (ws + WS_MWDE_G);
    float*    colpart  = (float*)   (ws + WS_COLPART);
    float*    belpart  = (float*)   (ws + WS_BELPART);
    int*      bar      = (int*)     (ws + WS_BAR);
    float*    out      = (float*)d_out;

    hipMemsetAsync(bar, 0, BB * 64 * sizeof(int), stream);
    hipMemsetAsync(d_out, 0, sizeof(float), stream);

    build_rows<<<MM, 64, 0, stream>>>(H, row_deg, row_pad, row_offf);
    scan_rows<<<1, 512, 0, stream>>>(row_deg, row_ptr);
    fill_csr<<<MM, 64, 0, stream>>>(row_deg, row_pad, row_ptr, edge_csr);
    gather_weights<<<(LL * EMAX) / 256, 256, 0, stream>>>(w_de, mw_de, edge_csr,
                                                          row_ptr, wde_g, mwde_g);
    nbp_main<<<BB * RR, NT, 0, stream>>>(synd, errs, llrs, w_llr, mw_llr, rhos, resw,
                                         row_ptr, row_offf, edge_csr, wde_g, mwde_g,
                                         colpart, belpart, bar, out);
}

// Round 8
// 453.252 us; speedup vs baseline: 3.9826x; 1.0683x over previous
//
#include <hip/hip_runtime.h>

// M=512, N=2048, B=4, L=20, H density 0.02 (row weight ~41, col weight ~10).
#define MM 512
#define NN 2048
#define BB 4
#define LL 20
#define MAXDEG 128      // per-row cap (~13 sigma)
#define EMAX  24576     // edge cap; actual E ~20973
#define NT    1024
#define RR    8         // blocks per batch (row-partitioned)
#define ROWSB 64        // MM / RR rows per block
#define SLOTS 4096      // padded edge slots per block (~2621 expected, +29 sigma)
#define COLSB 256       // NN / RR loss columns per block
#define EPSV  1e-6f

// ---------------- workspace layout (bytes) ----------------
#define WS_ROW_DEG   0          // int[512]
#define WS_ROW_PAD   2048       // int[512*128]
#define WS_ROW_OFFF  264192     // float[512]
#define WS_ROW_PTR   266240     // int[513] (pad to 268416)
#define WS_EDGE_CSR  268416     // uint[EMAX] (row<<16|col), CSR order
#define WS_WDE_P     366720     // float[L*RR*SLOTS]  per-block padded, 16B-aligned segs
#define WS_MWDE_P    2988160    // float[L*RR*SLOTS]
#define WS_COLPART   5609600    // float[2*B*RR*NN]  (layer-parity double buffer)
#define WS_BELPART   6133888    // float[2*B*RR*NN]
#define WS_BAR       6658176    // int[B*64] barrier counters (memset 0 each launch)
// total ~6.66 MB

// ---- k1: one wave per row, ballot-compact H row into padded list ----
__global__ __launch_bounds__(64)
void build_rows(const float* __restrict__ H, int* __restrict__ row_deg,
                int* __restrict__ row_pad, float* __restrict__ row_offf) {
    int i = blockIdx.x, lane = threadIdx.x;
    const float* hrow = H + (size_t)i * NN;
    int base = 0;
    for (int chunk = 0; chunk < NN / 64; ++chunk) {
        int c = chunk * 64 + lane;
        bool pred = hrow[c] != 0.0f;
        unsigned long long mask = __ballot(pred);
        int before = __popcll(mask & ((1ull << lane) - 1ull));
        if (pred) {
            int idx = base + before;
            if (idx < MAXDEG) row_pad[i * MAXDEG + idx] = c;
        }
        base += __popcll(mask);
    }
    if (lane == 0) {
        row_deg[i] = base < MAXDEG ? base : MAXDEG;
        // off-support entries contribute clip(1.0)=1-eps each to the row product
        row_offf[i] = powf(1.0f - EPSV, (float)(NN - base));
    }
}

// ---- k2: exclusive prefix sum of row degrees (single block) ----
__global__ __launch_bounds__(512)
void scan_rows(const int* __restrict__ row_deg, int* __restrict__ row_ptr) {
    __shared__ int tmp[512];
    int t = threadIdx.x;
    tmp[t] = row_deg[t];
    __syncthreads();
    for (int off = 1; off < 512; off <<= 1) {
        int v = (t >= off) ? tmp[t - off] : 0;
        __syncthreads();
        tmp[t] += v;
        __syncthreads();
    }
    if (t == 0) row_ptr[0] = 0;
    row_ptr[t + 1] = tmp[t];
}

// ---- k3: fill CSR edge list ----
__global__ __launch_bounds__(64)
void fill_csr(const int* __restrict__ row_deg, const int* __restrict__ row_pad,
              const int* __restrict__ row_ptr, unsigned* __restrict__ edge_csr) {
    int i = blockIdx.x, lane = threadIdx.x;
    int deg = row_deg[i], base = row_ptr[i];
    for (int k = lane; k < deg; k += 64)
        edge_csr[base + k] = ((unsigned)i << 16) | (unsigned)row_pad[i * MAXDEG + k];
}

// ---- k4: gather dense weights into per-block padded segments ----
// layout: [l][r][s], segment bases 16B-aligned -> float4 loads in nbp_main
__global__ __launch_bounds__(256)
void gather_weights(const float* __restrict__ w_de, const float* __restrict__ mw_de,
                    const unsigned* __restrict__ edge_csr, const int* __restrict__ row_ptr,
                    float* __restrict__ wde_p, float* __restrict__ mwde_p) {
    int idx = blockIdx.x * 256 + threadIdx.x;       // 0 .. L*RR*SLOTS-1
    int l = idx / (RR * SLOTS);
    int rem = idx - l * (RR * SLOTS);
    int r = rem / SLOTS, s = rem - r * SLOTS;
    int e = row_ptr[r * ROWSB] + s;
    if (e < row_ptr[(r + 1) * ROWSB]) {
        unsigned pk = edge_csr[e];
        size_t src = (size_t)l * MM * NN + (size_t)(pk >> 16) * NN + (pk & 0xffffu);
        wde_p[idx]  = w_de[src];
        mwde_p[idx] = mw_de[src];
    } else {
        wde_p[idx]  = 0.0f;    // padded slots: defined zeros
        mwde_p[idx] = 0.0f;
    }
}

// ---- device-scope barrier across the RR blocks of one batch ----
// Fresh counter per instance (no ABA). tid0: release fence -> add -> spin -> acquire.
__device__ __forceinline__ void grid_barrier(int* ctr) {
    __syncthreads();
    if (threadIdx.x == 0) {
        __threadfence();
        __hip_atomic_fetch_add(ctr, 1, __ATOMIC_RELAXED, __HIP_MEMORY_SCOPE_AGENT);
        while (__hip_atomic_load(ctr, __ATOMIC_RELAXED, __HIP_MEMORY_SCOPE_AGENT) < RR)
            __builtin_amdgcn_s_sleep(1);
        __threadfence();
    }
    __syncthreads();
}

// ---- main BP kernel: 32 blocks = 4 batches x 8 row-partitions ----
__global__ __launch_bounds__(NT, 4)
void nbp_main(const int* __restrict__ synd, const int* __restrict__ errs,
              const float* __restrict__ llrs,
              const float* __restrict__ w_llr, const float* __restrict__ mw_llr,
              const float* __restrict__ rhos, const float* __restrict__ resw,
              const int* __restrict__ row_ptr, const float* __restrict__ row_offf,
              const unsigned* __restrict__ edge_csr,
              const float* __restrict__ wde_p, const float* __restrict__ mwde_p,
              float* __restrict__ colpart, float* __restrict__ belpart,
              int* __restrict__ bar, float* __restrict__ out) {
    __shared__ float d_sb[SLOTS];         // 16 KB, block-local d, float4 stores
    __shared__ float colsum_s[NN];        // total colsum for current layer
    __shared__ float bel_s[NN];           // belief partial (edge contributions)
    __shared__ float ncs_s[NN];           // next-layer colsum partial
    __shared__ float llrs_s[NN];
    __shared__ float rowprod_s[ROWSB];
    __shared__ float rp_coef[ROWSB];      // row_offf * (-1)^syndrome
    __shared__ int   rowptr_s[ROWSB + 1];
    __shared__ float rho_n[LL];
    __shared__ float red[16];

    const int blk = blockIdx.x;
    const int b = blk & 3, r = blk >> 2;
    const int i0 = r * ROWSB;
    const int tid = threadIdx.x;
    const int lane = tid & 63, wave = tid >> 6;

    int* bar_b = bar + b * 64;

    // ---- prologue ----
    if (tid == 0) {
        float mx = -1e30f;
        for (int l = 0; l < LL; ++l) mx = fmaxf(mx, rhos[l]);
        float s = 0.0f;
        for (int l = 0; l < LL; ++l) { float e = __expf(rhos[l] - mx); rho_n[l] = e; s += e; }
        for (int l = 0; l < LL; ++l) rho_n[l] /= s;
    }
    if (tid < ROWSB) {
        int i = i0 + tid;
        rowptr_s[tid] = row_ptr[i];
        rp_coef[tid] = row_offf[i] * (1.0f - 2.0f * (float)synd[b * MM + i]);
    }
    if (tid == ROWSB) rowptr_s[ROWSB] = row_ptr[i0 + ROWSB];
    for (int j = tid; j < NN; j += NT) {
        float lj = llrs[j];
        llrs_s[j] = lj;
        colsum_s[j] = lj * w_llr[j];       // layer-0 colsum: msgs are zero
    }

    const int e_lo = row_ptr[i0], e_hi = row_ptr[i0 + ROWSB];
    const int cnt = e_hi - e_lo;
    const int s0 = 4 * tid;                // this thread's first local slot

    // per-thread contiguous edge state
    unsigned idx[4];
    float msg[4], d_r[4];
    #pragma unroll
    for (int k = 0; k < 4; ++k) {
        int e = e_lo + s0 + k;
        idx[k] = edge_csr[(s0 + k) < cnt ? e : e_lo] - ((unsigned)i0 << 16);
        msg[k] = 0.0f;
    }
    __syncthreads();

    float loss = 0.0f;

    for (int l = 0; l < LL; ++l) {
        const float rw = resw[l];
        const int par = l & 1;
        float* colpart_b = colpart + ((size_t)par * BB + b) * RR * NN;
        float* belpart_b = belpart + ((size_t)par * BB + b) * RR * NN;

        // ---- B: prefetch weights (aligned float4) + per-edge tanh ----
        const float4 mq = *(const float4*)(mwde_p + ((size_t)(l * RR + r) * SLOTS) + s0);
        float4 wq = make_float4(0.f, 0.f, 0.f, 0.f);
        if (l + 1 < LL)
            wq = *(const float4*)(wde_p + ((size_t)((l + 1) * RR + r) * SLOTS) + s0);
        const float mv[4] = {mq.x, mq.y, mq.z, mq.w};
        const float wn[4] = {wq.x, wq.y, wq.z, wq.w};

        #pragma unroll
        for (int k = 0; k < 4; ++k) {
            int j = idx[k] & 0xffffu;
            float en = colsum_s[j] - msg[k];
            float t = __expf(en);                             // tanh(en/2)=1-2/(e^en+1)
            float d = 1.0f - 2.0f * __builtin_amdgcn_rcpf(t + 1.0f);
            if (d == 0.0f) d = 1.0f;                          // ref: where(d==0,1,d)
            d = fminf(fmaxf(d, -1.0f + EPSV), 1.0f - EPSV);
            d_r[k] = d;
        }
        *(float4*)&d_sb[s0] = make_float4(d_r[0], d_r[1], d_r[2], d_r[3]);
        __syncthreads();

        // ---- C: row products, 4 threads/row | zero bel/ncs partials ----
        if (tid < 4 * ROWSB) {
            int i = tid >> 2, q = tid & 3;
            int s = rowptr_s[i] - e_lo;
            int deg = rowptr_s[i + 1] - rowptr_s[i];
            float p = 1.0f;
            for (int c = q; c < deg; c += 4) p *= d_sb[s + c];
            p *= __shfl_xor(p, 1);
            p *= __shfl_xor(p, 2);
            if (q == 0) rowprod_s[i] = p * rp_coef[i];        // sign folded in
        } else {
            for (int j = tid - 4 * ROWSB; j < NN; j += NT - 4 * ROWSB) {
                bel_s[j] = 0.0f;
                ncs_s[j] = 0.0f;
            }
        }
        __syncthreads();

        // ---- D: atanh + msg update + dual scatter (bel + next colsum) ----
        #pragma unroll
        for (int k = 0; k < 4; ++k) {
            int il = idx[k] >> 16;
            int j  = idx[k] & 0xffffu;
            float rq = rowprod_s[il] * __builtin_amdgcn_rcpf(d_r[k]);
            // sgn*2*atanh(x) = 2*atanh(sgn*x); sgn folded into rp_coef
            float v = __logf(1.0f + rq) - __logf(1.0f - rq) + rw * msg[k];
            msg[k] = v;
            if (s0 + k < cnt) {
                atomicAdd(&bel_s[j], v * mv[k]);
                if (l + 1 < LL) atomicAdd(&ncs_s[j], v * wn[k]);
            }
        }
        __syncthreads();
        for (int j = tid; j < NN; j += NT) {
            belpart_b[r * NN + j] = bel_s[j];
            colpart_b[r * NN + j] = ncs_s[j];
        }
        grid_barrier(&bar_b[l]);

        // ---- E: loss on column slice + total colsum for next layer ----
        if (tid < COLSB) {
            int j = r * COLSB + tid;
            float bel = llrs_s[j] * mw_llr[l * NN + j];
            const float* bp = belpart_b + j;
            #pragma unroll
            for (int r2 = 0; r2 < RR; ++r2) bel += bp[r2 * NN];
            float sp = fmaxf(bel, 0.0f) + log1pf(__expf(-fabsf(bel)));  // softplus
            loss += rho_n[l] * (sp - (1.0f - (float)errs[b * NN + j]) * bel);
        }
        if (l + 1 < LL) {
            const float* wl_next = w_llr + (l + 1) * NN;
            for (int j = tid; j < NN; j += NT) {
                float s = llrs_s[j] * wl_next[j];
                const float* cp = colpart_b + j;
                #pragma unroll
                for (int r2 = 0; r2 < RR; ++r2) s += cp[r2 * NN];
                colsum_s[j] = s;
            }
        }
        __syncthreads();
        // safe w.r.t. next layer: partial buffers are parity double-buffered,
        // so D(l+1) writes the other buffer while any straggler still reads this one.
    }

    // ---- block reduction of loss, then one global atomic ----
    #pragma unroll
    for (int off = 32; off > 0; off >>= 1) loss += __shfl_down(loss, off);
    if (lane == 0) red[wave] = loss;
    __syncthreads();
    if (wave == 0) {
        float v = (lane < 16) ? red[lane] : 0.0f;
        #pragma unroll
        for (int off = 8; off > 0; off >>= 1) v += __shfl_down(v, off);
        if (lane == 0) atomicAdd(out, v * 0.25f);
    }
}

extern "C" void kernel_launch(void* const* d_in, const int* in_sizes, int n_in,
                              void* d_out, int out_size, void* d_ws, size_t ws_size,
                              hipStream_t stream) {
    const int*   synd  = (const int*)  d_in[0];
    const int*   errs  = (const int*)  d_in[1];
    const float* H     = (const float*)d_in[2];
    const float* llrs  = (const float*)d_in[3];
    const float* w_de  = (const float*)d_in[4];
    const float* w_llr = (const float*)d_in[5];
    const float* mw_de = (const float*)d_in[6];
    const float* mw_llr= (const float*)d_in[7];
    const float* rhos  = (const float*)d_in[8];
    const float* resw  = (const float*)d_in[9];

    char* ws = (char*)d_ws;
    int*      row_deg  = (int*)     (ws + WS_ROW_DEG);
    int*      row_pad  = (int*)     (ws + WS_ROW_PAD);
    float*    row_offf = (float*)   (ws + WS_ROW_OFFF);
    int*      row_ptr  = (int*)     (ws + WS_ROW_PTR);
    unsigned* edge_csr = (unsigned*)(ws + WS_EDGE_CSR);
    float*    wde_p    = (float*)   (ws + WS_WDE_P);
    float*    mwde_p   = (float*)   (ws + WS_MWDE_P);
    float*    colpart  = (float*)   (ws + WS_COLPART);
    float*    belpart  = (float*)   (ws + WS_BELPART);
    int*      bar      = (int*)     (ws + WS_BAR);
    float*    out      = (float*)d_out;

    hipMemsetAsync(bar, 0, BB * 64 * sizeof(int), stream);
    hipMemsetAsync(d_out, 0, sizeof(float), stream);

    build_rows<<<MM, 64, 0, stream>>>(H, row_deg, row_pad, row_offf);
    scan_rows<<<1, 512, 0, stream>>>(row_deg, row_ptr);
    fill_csr<<<MM, 64, 0, stream>>>(row_deg, row_pad, row_ptr, edge_csr);
    gather_weights<<<(LL * RR * SLOTS) / 256, 256, 0, stream>>>(w_de, mw_de, edge_csr,
                                                                row_ptr, wde_p, mwde_p);
    nbp_main<<<BB * RR, NT, 0, stream>>>(synd, errs, llrs, w_llr, mw_llr, rhos, resw,
                                         row_ptr, row_offf, edge_csr, wde_p, mwde_p,
                                         colpart, belpart, bar, out);
}